// Round 2
// baseline (183.755 us; speedup 1.0000x reference)
//
#include <hip/hip_runtime.h>
#include <stdint.h>
#include <stddef.h>

typedef _Float16 h2 __attribute__((ext_vector_type(2)));
typedef _Float16 h8 __attribute__((ext_vector_type(8)));
typedef float f4 __attribute__((ext_vector_type(4)));

union Hfrag { h2 p[4]; h8 v; };

// ---------------- workspace layout (bytes) ----------------
// pmin/pmax (K1 partials) are dead after K2; Bt (built in K3) overlays pmin.
#define WS_PMIN   0               // f32 [512][256] = 512 KB
#define WS_PMAX   524288          // f32 [512][256] = 512 KB
#define WS_BT     0               // f16 [40 ks][2 half][128 o][32 kk] = 655,360 B
#define WS_SMALL  1048576
#define WS_SCALEV (WS_SMALL + 0)      // f32 [256]
#define WS_BKN    (WS_SMALL + 1024)   // f16 [4][256] knot offsets b_j
#define WS_C0     (WS_SMALL + 3072)   // f32 [256] folded constant column
#define WS_BSC    (WS_SMALL + 4096)
#define WS_BSH    (WS_SMALL + 5120)
#define WS_SSC    (WS_SMALL + 6144)
#define WS_SSH    (WS_SMALL + 7168)

// ---------------- K1: per-feature min/max partials ----------------
__global__ __launch_bounds__(256) void kan_minmax(const float* __restrict__ x,
                                                  float* __restrict__ pmin,
                                                  float* __restrict__ pmax) {
  __shared__ f4 smn[4][64], smx[4][64];
  const int b = blockIdx.x, t = threadIdx.x;
  const int fq = t & 63, rg = t >> 6;
  const float* p = x + (size_t)b * 64 * 256 + (size_t)rg * 16 * 256 + fq * 4;
  f4 mn = (f4)(3.402823466e38f), mx = (f4)(-3.402823466e38f);
#pragma unroll
  for (int j = 0; j < 16; ++j) {
    f4 v = *(const f4*)(p + (size_t)j * 256);
    mn = __builtin_elementwise_min(mn, v);
    mx = __builtin_elementwise_max(mx, v);
  }
  smn[rg][fq] = mn; smx[rg][fq] = mx;
  __syncthreads();
  if (rg == 0) {
#pragma unroll
    for (int g = 1; g < 4; ++g) {
      mn = __builtin_elementwise_min(mn, smn[g][fq]);
      mx = __builtin_elementwise_max(mx, smx[g][fq]);
    }
    *(f4*)(pmin + (size_t)b * 256 + fq * 4) = mn;
    *(f4*)(pmax + (size_t)b * 256 + fq * 4) = mx;
  }
}

// ---------------- K2: finalize minmax -> scalev, knot offsets, BN consts ----
// 4 blocks x 256 threads; block bd covers features bd*64..bd*64+63.
// b_j = mn + j*0.25*(mx-mn+eps): relu(xn - j/4) == scalev * relu(x - b_j).
__global__ __launch_bounds__(256) void kan_finalize(
    const float* __restrict__ pmin, const float* __restrict__ pmax,
    const float* __restrict__ g1, const float* __restrict__ b1,
    const float* __restrict__ m1, const float* __restrict__ v1,
    const float* __restrict__ g2, const float* __restrict__ b2,
    const float* __restrict__ m2, const float* __restrict__ v2,
    float* __restrict__ scalev, _Float16* __restrict__ bkn,
    float* __restrict__ bscv, float* __restrict__ bshv,
    float* __restrict__ sscv, float* __restrict__ sshv) {
  __shared__ float smn[4][64], smx[4][64];
  const int t = threadIdx.x;
  const int ol = t & 63, pg = t >> 6;
  const int o = blockIdx.x * 64 + ol;
  float mn = 3.402823466e38f, mx = -3.402823466e38f;
  for (int p = pg * 128; p < pg * 128 + 128; ++p) {
    mn = fminf(mn, pmin[(size_t)p * 256 + o]);
    mx = fmaxf(mx, pmax[(size_t)p * 256 + o]);
  }
  smn[pg][ol] = mn; smx[pg][ol] = mx;
  __syncthreads();
  if (pg == 0) {
#pragma unroll
    for (int g = 1; g < 4; ++g) {
      mn = fminf(mn, smn[g][ol]);
      mx = fmaxf(mx, smx[g][ol]);
    }
    const float rng = mx - mn + 1e-7f;
    scalev[o] = 1.0f / rng;
    const float step = 0.25f * rng;
#pragma unroll
    for (int j = 0; j < 4; ++j)
      bkn[j * 256 + o] = (_Float16)(mn + step * (float)j);
    const float bs = g1[o] / sqrtf(v1[o] + 1e-3f);
    bscv[o] = bs;
    bshv[o] = b1[o] - m1[o] * bs;
    const float ss = g2[o] / sqrtf(v2[o] + 1e-3f);
    sscv[o] = ss;
    sshv[o] = b2[o] - m2[o] * ss;
  }
}

// ---------------- K3: build reduced f16 weight matrix Bt + C0 ----------------
// The 8 triangle bases on xn in [0,1) span {1, xn, relu(xn-1/4), relu(xn-1/2),
// relu(xn-3/4)}.  Coefs per knot k (t=-1+0.25k):
//   k=1..4: tri_k = (0.25k) - xn + [k<4: relu(xn-k/4)]
//   k=5..7: tri_k = (2-0.25k) + xn - 2*relu(xn-(k-4)/4)
//   k=8   : tri_8 = xn
// Const column folds into BN shift via C0[o] = sum_i w'0*s.  Scale sc_i folds
// into Bt so the GEMM's A-columns are relu(x - b_j) on raw x (f16).
// Bt flat: [(ks*2 + half)*128 + o]*32 + kk ; ks = j*8+ic (spline j=0..3),
// ks = 32+ic (base, value = base_w[i, o]).  i = ic*32+kk.
__global__ __launch_bounds__(256) void kan_buildw(
    const float* __restrict__ spline_w, const float* __restrict__ spline_s,
    const float* __restrict__ base_w, const float* __restrict__ scalev,
    _Float16* __restrict__ Bt, float* __restrict__ C0) {
  const int og = blockIdx.x;   // 256 blocks: one output feature each
  const int i  = threadIdx.x;  // input feature
  const float* wp = spline_w + (size_t)(og * 256 + i) * 9;
  const float w1 = wp[1], w2 = wp[2], w3 = wp[3], w4 = wp[4];
  const float w5 = wp[5], w6 = wp[6], w7 = wp[7], w8 = wp[8];
  const float s  = spline_s[og * 256 + i];
  const float sc = scalev[i];
  const float wp0 = 0.25f*w1 + 0.5f*w2 + 0.75f*w3 + w4 + 0.75f*w5 + 0.5f*w6 + 0.25f*w7;
  float wj[4];
  wj[0] = (w5 + w6 + w7 + w8) - (w1 + w2 + w3 + w4);  // xn column
  wj[1] = w1 - 2.0f * w5;                             // relu(xn-1/4)
  wj[2] = w2 - 2.0f * w6;                             // relu(xn-1/2)
  wj[3] = w3 - 2.0f * w7;                             // relu(xn-3/4)
  const float ssc = s * sc;
  const int half = og >> 7, o = og & 127, ic = i >> 5, kk = i & 31;
#pragma unroll
  for (int j = 0; j < 4; ++j) {
    const int ks = j * 8 + ic;
    Bt[((size_t)(ks * 2 + half) * 128 + o) * 32 + kk] = (_Float16)(wj[j] * ssc);
  }
  // base GEMM weights (unchanged math)
  Bt[((size_t)((32 + ic) * 2 + half) * 128 + o) * 32 + kk] =
      (_Float16)base_w[(size_t)i * 256 + og];
  // C0[og] = sum_i wp0 * s  (constant column, folded into spline-BN shift)
  __shared__ float red[256];
  red[i] = wp0 * s;
  __syncthreads();
  for (int st = 128; st > 0; st >>= 1) {
    if (i < st) red[i] += red[i + st];
    __syncthreads();
  }
  if (i == 0) C0[og] = red[0];
}

// ---------------- K4: fused dual GEMM + BN + SiLU ----------------
// 128x128 tile, 4 waves (2x2), 16x16x32 f16 MFMA.  Per K-chunk of 32 inputs:
// 5 MFMA sub-steps (4 spline cols + base) instead of 9.  A-gen for spline
// cols is 2 packed ops: relu(x_f16 - b_j).  B frags register-pipelined 1 step
// ahead from L2-resident Bt (640 KB).
__global__ __launch_bounds__(256, 2) void kan_gemm(
    const float* __restrict__ x, const _Float16* __restrict__ Bt,
    const _Float16* __restrict__ bkn, const float* __restrict__ C0,
    const float* __restrict__ bscv, const float* __restrict__ bshv,
    const float* __restrict__ sscv, const float* __restrict__ sshv,
    float* __restrict__ out) {
  const int tid = threadIdx.x;
  const int lane = tid & 63;
  const int wv = tid >> 6;
  const int wm = wv >> 1, wn = wv & 1;
  const int lr = lane & 15, lg = lane >> 4;
  const int mt = blockIdx.x & 255, nt = blockIdx.x >> 8;

  const int rowA = mt * 128 + wm * 64 + lr;
  const int colB = wn * 64 + lr;

  f4 accS[4][4], accB[4][4];
#pragma unroll
  for (int m = 0; m < 4; ++m)
#pragma unroll
    for (int n = 0; n < 4; ++n) { accS[m][n] = (f4)0.0f; accB[m][n] = (f4)0.0f; }

  const char* btbase = (const char*)Bt + (size_t)nt * 8192 + (size_t)colB * 64 + (size_t)lg * 16;

  h2 hz; hz[0] = (_Float16)0.0f; hz[1] = (_Float16)0.0f;

  f4 xa[4], xb[4];
  { // prologue: x fragment for ic=0
    const int ib = lg * 8;
#pragma unroll
    for (int m = 0; m < 4; ++m) {
      const float* px = x + (size_t)(rowA + m * 16) * 256 + ib;
      xa[m] = *(const f4*)px; xb[m] = *(const f4*)(px + 4);
    }
  }

#pragma unroll 1
  for (int ic = 0; ic < 8; ++ic) {
    // knot offsets b_j for this input chunk (per-lane h8 = 8 consecutive i)
    Hfrag bb[4];
#pragma unroll
    for (int j = 0; j < 4; ++j)
      bb[j].v = *(const h8*)(bkn + j * 256 + ic * 32 + lg * 8);

    // x -> f16 (RTE), A-fragment layout
    Hfrag xh[4];
#pragma unroll
    for (int m = 0; m < 4; ++m) {
      xh[m].p[0][0] = (_Float16)xa[m].x; xh[m].p[0][1] = (_Float16)xa[m].y;
      xh[m].p[1][0] = (_Float16)xa[m].z; xh[m].p[1][1] = (_Float16)xa[m].w;
      xh[m].p[2][0] = (_Float16)xb[m].x; xh[m].p[2][1] = (_Float16)xb[m].y;
      xh[m].p[3][0] = (_Float16)xb[m].z; xh[m].p[3][1] = (_Float16)xb[m].w;
    }

    // prefetch next chunk's x early (xa/xb dead after conversion)
    if (ic < 7) {
      const int ib = (ic + 1) * 32 + lg * 8;
#pragma unroll
      for (int m = 0; m < 4; ++m) {
        const float* px = x + (size_t)(rowA + m * 16) * 256 + ib;
        xa[m] = *(const f4*)px; xb[m] = *(const f4*)(px + 4);
      }
    }

    const char* bpic = btbase + (size_t)ic * 16384;
    Hfrag bf[4];
#pragma unroll
    for (int n = 0; n < 4; ++n) bf[n].v = *(const h8*)(bpic + n * 1024);

#pragma unroll
    for (int it = 0; it < 5; ++it) {   // it 0..3: spline cols; it 4: base
      Hfrag bnx[4];
      if (it < 4) {                    // pipeline next sub-step's B frags
        const char* bp = bpic + (size_t)(it + 1) * 131072;
#pragma unroll
        for (int n = 0; n < 4; ++n) bnx[n].v = *(const h8*)(bp + n * 1024);
      }
      if (it < 4) {
        Hfrag af[4];
#pragma unroll
        for (int m = 0; m < 4; ++m)
#pragma unroll
          for (int q = 0; q < 4; ++q) {
            h2 d = xh[m].p[q] - bb[it].p[q];
            af[m].p[q] = __builtin_elementwise_max(d, hz);
          }
#pragma unroll
        for (int m = 0; m < 4; ++m)
#pragma unroll
          for (int n = 0; n < 4; ++n)
            accS[m][n] = __builtin_amdgcn_mfma_f32_16x16x32_f16(af[m].v, bf[n].v, accS[m][n], 0, 0, 0);
      } else {
        // base step: A = f16(x) verbatim
#pragma unroll
        for (int m = 0; m < 4; ++m)
#pragma unroll
          for (int n = 0; n < 4; ++n)
            accB[m][n] = __builtin_amdgcn_mfma_f32_16x16x32_f16(xh[m].v, bf[n].v, accB[m][n], 0, 0, 0);
      }
      if (it < 4) {
#pragma unroll
        for (int n = 0; n < 4; ++n) bf[n] = bnx[n];
      }
    }
  }

  // epilogue: out = silu(accB*bs + bsh) + accS*ss + (ssh + ss*C0)
#pragma unroll
  for (int n = 0; n < 4; ++n) {
    const int col = nt * 128 + colB + n * 16;
    const float vbs = bscv[col], vbh = bshv[col];
    const float vss = sscv[col];
    const float vsh = sshv[col] + vss * C0[col];
#pragma unroll
    for (int m = 0; m < 4; ++m) {
      const int row0 = mt * 128 + wm * 64 + m * 16 + lg * 4;
#pragma unroll
      for (int r = 0; r < 4; ++r) {
        const float zb = accB[m][n][r] * vbs + vbh;
        const float si = zb / (1.0f + __expf(-zb));
        const float val = si + accS[m][n][r] * vss + vsh;
        out[(size_t)(row0 + r) * 256 + col] = val;
      }
    }
  }
}

extern "C" void kernel_launch(void* const* d_in, const int* in_sizes, int n_in,
                              void* d_out, int out_size, void* d_ws, size_t ws_size,
                              hipStream_t stream) {
  const float* x        = (const float*)d_in[0];
  const float* base_w   = (const float*)d_in[1];
  const float* spline_w = (const float*)d_in[2];
  const float* spline_s = (const float*)d_in[3];
  const float* g1 = (const float*)d_in[4];
  const float* b1 = (const float*)d_in[5];
  const float* m1 = (const float*)d_in[6];
  const float* v1 = (const float*)d_in[7];
  const float* g2 = (const float*)d_in[8];
  const float* b2 = (const float*)d_in[9];
  const float* m2 = (const float*)d_in[10];
  const float* v2 = (const float*)d_in[11];
  float* out = (float*)d_out;
  char* ws = (char*)d_ws;

  float* pmin     = (float*)(ws + WS_PMIN);
  float* pmax     = (float*)(ws + WS_PMAX);
  _Float16* Bt    = (_Float16*)(ws + WS_BT);
  float* scalev   = (float*)(ws + WS_SCALEV);
  _Float16* bkn   = (_Float16*)(ws + WS_BKN);
  float* C0       = (float*)(ws + WS_C0);
  float* bscv     = (float*)(ws + WS_BSC);
  float* bshv     = (float*)(ws + WS_BSH);
  float* sscv     = (float*)(ws + WS_SSC);
  float* sshv     = (float*)(ws + WS_SSH);

  kan_minmax<<<512, 256, 0, stream>>>(x, pmin, pmax);
  kan_finalize<<<4, 256, 0, stream>>>(pmin, pmax, g1, b1, m1, v1, g2, b2, m2, v2,
                                      scalev, bkn, bscv, bshv, sscv, sshv);
  kan_buildw<<<256, 256, 0, stream>>>(spline_w, spline_s, base_w, scalev, Bt, C0);
  kan_gemm<<<512, 256, 0, stream>>>(x, Bt, bkn, C0, bscv, bshv, sscv, sshv, out);
}

// Round 3
// 155.044 us; speedup vs baseline: 1.1852x; 1.1852x over previous
//
#include <hip/hip_runtime.h>
#include <stdint.h>
#include <stddef.h>

typedef _Float16 h2 __attribute__((ext_vector_type(2)));
typedef _Float16 h8 __attribute__((ext_vector_type(8)));
typedef float f4 __attribute__((ext_vector_type(4)));

union Hfrag { h2 p[4]; h8 v; };

// ---------------- workspace layout (bytes) ----------------
// pmin/pmax (K1 partials) are dead after K2; Bt (built in K3) overlays pmin.
#define WS_PMIN   0               // f32 [512][256] = 512 KB
#define WS_PMAX   524288          // f32 [512][256] = 512 KB
#define WS_BT     0               // f16 [40 ks][2 half][128 o][32 kk] = 655,360 B
#define WS_SMALL  1048576
#define WS_SCALEV (WS_SMALL + 0)      // f32 [256]
#define WS_BKN    (WS_SMALL + 1024)   // f16 [4][256] knot offsets b_j
#define WS_C0     (WS_SMALL + 3072)   // f32 [256] folded constant column
#define WS_BSC    (WS_SMALL + 4096)
#define WS_BSH    (WS_SMALL + 5120)
#define WS_SSC    (WS_SMALL + 6144)
#define WS_SSH    (WS_SMALL + 7168)

// ---------------- K1: per-feature min/max partials ----------------
__global__ __launch_bounds__(256) void kan_minmax(const float* __restrict__ x,
                                                  float* __restrict__ pmin,
                                                  float* __restrict__ pmax) {
  __shared__ f4 smn[4][64], smx[4][64];
  const int b = blockIdx.x, t = threadIdx.x;
  const int fq = t & 63, rg = t >> 6;
  const float* p = x + (size_t)b * 64 * 256 + (size_t)rg * 16 * 256 + fq * 4;
  f4 mn = (f4)(3.402823466e38f), mx = (f4)(-3.402823466e38f);
#pragma unroll
  for (int j = 0; j < 16; ++j) {
    f4 v = *(const f4*)(p + (size_t)j * 256);
    mn = __builtin_elementwise_min(mn, v);
    mx = __builtin_elementwise_max(mx, v);
  }
  smn[rg][fq] = mn; smx[rg][fq] = mx;
  __syncthreads();
  if (rg == 0) {
#pragma unroll
    for (int g = 1; g < 4; ++g) {
      mn = __builtin_elementwise_min(mn, smn[g][fq]);
      mx = __builtin_elementwise_max(mx, smx[g][fq]);
    }
    *(f4*)(pmin + (size_t)b * 256 + fq * 4) = mn;
    *(f4*)(pmax + (size_t)b * 256 + fq * 4) = mx;
  }
}

// ---------------- K2: finalize minmax -> scalev, knot offsets, BN consts ----
// b_j = mn + j*0.25*(mx-mn+eps): relu(xn - j/4) == scalev * relu(x - b_j).
__global__ __launch_bounds__(256) void kan_finalize(
    const float* __restrict__ pmin, const float* __restrict__ pmax,
    const float* __restrict__ g1, const float* __restrict__ b1,
    const float* __restrict__ m1, const float* __restrict__ v1,
    const float* __restrict__ g2, const float* __restrict__ b2,
    const float* __restrict__ m2, const float* __restrict__ v2,
    float* __restrict__ scalev, _Float16* __restrict__ bkn,
    float* __restrict__ bscv, float* __restrict__ bshv,
    float* __restrict__ sscv, float* __restrict__ sshv) {
  __shared__ float smn[4][64], smx[4][64];
  const int t = threadIdx.x;
  const int ol = t & 63, pg = t >> 6;
  const int o = blockIdx.x * 64 + ol;
  float mn = 3.402823466e38f, mx = -3.402823466e38f;
  for (int p = pg * 128; p < pg * 128 + 128; ++p) {
    mn = fminf(mn, pmin[(size_t)p * 256 + o]);
    mx = fmaxf(mx, pmax[(size_t)p * 256 + o]);
  }
  smn[pg][ol] = mn; smx[pg][ol] = mx;
  __syncthreads();
  if (pg == 0) {
#pragma unroll
    for (int g = 1; g < 4; ++g) {
      mn = fminf(mn, smn[g][ol]);
      mx = fmaxf(mx, smx[g][ol]);
    }
    const float rng = mx - mn + 1e-7f;
    scalev[o] = 1.0f / rng;
    const float step = 0.25f * rng;
#pragma unroll
    for (int j = 0; j < 4; ++j)
      bkn[j * 256 + o] = (_Float16)(mn + step * (float)j);
    const float bs = g1[o] / sqrtf(v1[o] + 1e-3f);
    bscv[o] = bs;
    bshv[o] = b1[o] - m1[o] * bs;
    const float ss = g2[o] / sqrtf(v2[o] + 1e-3f);
    sscv[o] = ss;
    sshv[o] = b2[o] - m2[o] * ss;
  }
}

// ---------------- K3: build reduced f16 weight matrix Bt + C0 ----------------
// 8 triangle bases on xn in [0,1) span {1, xn, relu(xn-1/4), relu(xn-1/2),
// relu(xn-3/4)}.  Const column -> C0 (folded into spline-BN shift); scale sc
// folds into Bt so GEMM A-columns are relu(x - b_j) on raw x (f16).
// Bt flat: [(ks*2 + half)*128 + o]*32 + kk ; ks = j*8+ic (spline j=0..3),
// ks = 32+ic (base, value = base_w[i, o]).  i = ic*32+kk.
__global__ __launch_bounds__(256) void kan_buildw(
    const float* __restrict__ spline_w, const float* __restrict__ spline_s,
    const float* __restrict__ base_w, const float* __restrict__ scalev,
    _Float16* __restrict__ Bt, float* __restrict__ C0) {
  const int og = blockIdx.x;   // 256 blocks: one output feature each
  const int i  = threadIdx.x;  // input feature
  const float* wp = spline_w + (size_t)(og * 256 + i) * 9;
  const float w1 = wp[1], w2 = wp[2], w3 = wp[3], w4 = wp[4];
  const float w5 = wp[5], w6 = wp[6], w7 = wp[7], w8 = wp[8];
  const float s  = spline_s[og * 256 + i];
  const float sc = scalev[i];
  const float wp0 = 0.25f*w1 + 0.5f*w2 + 0.75f*w3 + w4 + 0.75f*w5 + 0.5f*w6 + 0.25f*w7;
  float wj[4];
  wj[0] = (w5 + w6 + w7 + w8) - (w1 + w2 + w3 + w4);  // xn column
  wj[1] = w1 - 2.0f * w5;                             // relu(xn-1/4)
  wj[2] = w2 - 2.0f * w6;                             // relu(xn-1/2)
  wj[3] = w3 - 2.0f * w7;                             // relu(xn-3/4)
  const float ssc = s * sc;
  const int half = og >> 7, o = og & 127, ic = i >> 5, kk = i & 31;
#pragma unroll
  for (int j = 0; j < 4; ++j) {
    const int ks = j * 8 + ic;
    Bt[((size_t)(ks * 2 + half) * 128 + o) * 32 + kk] = (_Float16)(wj[j] * ssc);
  }
  Bt[((size_t)((32 + ic) * 2 + half) * 128 + o) * 32 + kk] =
      (_Float16)base_w[(size_t)i * 256 + og];
  __shared__ float red[256];
  red[i] = wp0 * s;
  __syncthreads();
  for (int st = 128; st > 0; st >>= 1) {
    if (i < st) red[i] += red[i + st];
    __syncthreads();
  }
  if (i == 0) C0[og] = red[0];
}

// ---------------- K4: fused dual GEMM + BN + SiLU ----------------
// 128x128 tile, 4 waves (2x2), 16x16x32 f16 MFMA.  5 MFMA sub-steps per
// K-chunk (4 spline cols + base).  B frags loaded straight from L2-resident
// Bt inside each sub-step (NO register pipeline: round-1's bnx copy-chain
// demoted fragment arrays to scratch -> +107 MB HBM writes).
__global__ __launch_bounds__(256, 2) void kan_gemm(
    const float* __restrict__ x, const _Float16* __restrict__ Bt,
    const _Float16* __restrict__ bkn, const float* __restrict__ C0,
    const float* __restrict__ bscv, const float* __restrict__ bshv,
    const float* __restrict__ sscv, const float* __restrict__ sshv,
    float* __restrict__ out) {
  const int tid = threadIdx.x;
  const int lane = tid & 63;
  const int wv = tid >> 6;
  const int wm = wv >> 1, wn = wv & 1;
  const int lr = lane & 15, lg = lane >> 4;
  const int mt = blockIdx.x & 255, nt = blockIdx.x >> 8;

  const int rowA = mt * 128 + wm * 64 + lr;
  const int colB = wn * 64 + lr;

  f4 accS[4][4], accB[4][4];
#pragma unroll
  for (int m = 0; m < 4; ++m)
#pragma unroll
    for (int n = 0; n < 4; ++n) { accS[m][n] = (f4)0.0f; accB[m][n] = (f4)0.0f; }

  const char* btbase = (const char*)Bt + (size_t)nt * 8192 + (size_t)colB * 64 + (size_t)lg * 16;

  h2 hz; hz[0] = (_Float16)0.0f; hz[1] = (_Float16)0.0f;

  f4 xa[4], xb[4];
  { // prologue: x fragment for ic=0
    const int ib = lg * 8;
#pragma unroll
    for (int m = 0; m < 4; ++m) {
      const float* px = x + (size_t)(rowA + m * 16) * 256 + ib;
      xa[m] = *(const f4*)px; xb[m] = *(const f4*)(px + 4);
    }
  }

#pragma unroll 1
  for (int ic = 0; ic < 8; ++ic) {
    // knot offsets b_j for this input chunk (8 consecutive i per lane group)
    Hfrag bb[4];
#pragma unroll
    for (int j = 0; j < 4; ++j)
      bb[j].v = *(const h8*)(bkn + j * 256 + ic * 32 + lg * 8);

    // x -> f16 (RTE), A-fragment layout
    Hfrag xh[4];
#pragma unroll
    for (int m = 0; m < 4; ++m) {
      xh[m].p[0][0] = (_Float16)xa[m].x; xh[m].p[0][1] = (_Float16)xa[m].y;
      xh[m].p[1][0] = (_Float16)xa[m].z; xh[m].p[1][1] = (_Float16)xa[m].w;
      xh[m].p[2][0] = (_Float16)xb[m].x; xh[m].p[2][1] = (_Float16)xb[m].y;
      xh[m].p[3][0] = (_Float16)xb[m].z; xh[m].p[3][1] = (_Float16)xb[m].w;
    }

    // prefetch next chunk's x early (xa/xb dead after conversion)
    if (ic < 7) {
      const int ib = (ic + 1) * 32 + lg * 8;
#pragma unroll
      for (int m = 0; m < 4; ++m) {
        const float* px = x + (size_t)(rowA + m * 16) * 256 + ib;
        xa[m] = *(const f4*)px; xb[m] = *(const f4*)(px + 4);
      }
    }

    const char* bpic = btbase + (size_t)ic * 16384;

    // 4 spline sub-steps: A = relu(x_f16 - b_j), accumulate into accS
#pragma unroll
    for (int it = 0; it < 4; ++it) {
      Hfrag bf[4];
#pragma unroll
      for (int n = 0; n < 4; ++n)
        bf[n].v = *(const h8*)(bpic + (size_t)it * 131072 + n * 1024);
      Hfrag af[4];
#pragma unroll
      for (int m = 0; m < 4; ++m)
#pragma unroll
        for (int q = 0; q < 4; ++q) {
          h2 d = xh[m].p[q] - bb[it].p[q];
          af[m].p[q] = __builtin_elementwise_max(d, hz);
        }
#pragma unroll
      for (int m = 0; m < 4; ++m)
#pragma unroll
        for (int n = 0; n < 4; ++n)
          accS[m][n] = __builtin_amdgcn_mfma_f32_16x16x32_f16(af[m].v, bf[n].v, accS[m][n], 0, 0, 0);
    }

    // base sub-step: A = f16(x) verbatim, accumulate into accB
    {
      Hfrag bf[4];
#pragma unroll
      for (int n = 0; n < 4; ++n)
        bf[n].v = *(const h8*)(bpic + 524288 + n * 1024);
#pragma unroll
      for (int m = 0; m < 4; ++m)
#pragma unroll
        for (int n = 0; n < 4; ++n)
          accB[m][n] = __builtin_amdgcn_mfma_f32_16x16x32_f16(xh[m].v, bf[n].v, accB[m][n], 0, 0, 0);
    }
  }

  // epilogue: out = silu(accB*bs + bsh) + accS*ss + (ssh + ss*C0)
#pragma unroll
  for (int n = 0; n < 4; ++n) {
    const int col = nt * 128 + colB + n * 16;
    const float vbs = bscv[col], vbh = bshv[col];
    const float vss = sscv[col];
    const float vsh = sshv[col] + vss * C0[col];
#pragma unroll
    for (int m = 0; m < 4; ++m) {
      const int row0 = mt * 128 + wm * 64 + m * 16 + lg * 4;
#pragma unroll
      for (int r = 0; r < 4; ++r) {
        const float zb = accB[m][n][r] * vbs + vbh;
        const float si = zb / (1.0f + __expf(-zb));
        const float val = si + accS[m][n][r] * vss + vsh;
        out[(size_t)(row0 + r) * 256 + col] = val;
      }
    }
  }
}

extern "C" void kernel_launch(void* const* d_in, const int* in_sizes, int n_in,
                              void* d_out, int out_size, void* d_ws, size_t ws_size,
                              hipStream_t stream) {
  const float* x        = (const float*)d_in[0];
  const float* base_w   = (const float*)d_in[1];
  const float* spline_w = (const float*)d_in[2];
  const float* spline_s = (const float*)d_in[3];
  const float* g1 = (const float*)d_in[4];
  const float* b1 = (const float*)d_in[5];
  const float* m1 = (const float*)d_in[6];
  const float* v1 = (const float*)d_in[7];
  const float* g2 = (const float*)d_in[8];
  const float* b2 = (const float*)d_in[9];
  const float* m2 = (const float*)d_in[10];
  const float* v2 = (const float*)d_in[11];
  float* out = (float*)d_out;
  char* ws = (char*)d_ws;

  float* pmin     = (float*)(ws + WS_PMIN);
  float* pmax     = (float*)(ws + WS_PMAX);
  _Float16* Bt    = (_Float16*)(ws + WS_BT);
  float* scalev   = (float*)(ws + WS_SCALEV);
  _Float16* bkn   = (_Float16*)(ws + WS_BKN);
  float* C0       = (float*)(ws + WS_C0);
  float* bscv     = (float*)(ws + WS_BSC);
  float* bshv     = (float*)(ws + WS_BSH);
  float* sscv     = (float*)(ws + WS_SSC);
  float* sshv     = (float*)(ws + WS_SSH);

  kan_minmax<<<512, 256, 0, stream>>>(x, pmin, pmax);
  kan_finalize<<<4, 256, 0, stream>>>(pmin, pmax, g1, b1, m1, v1, g2, b2, m2, v2,
                                      scalev, bkn, bscv, bshv, sscv, sshv);
  kan_buildw<<<256, 256, 0, stream>>>(spline_w, spline_s, base_w, scalev, Bt, C0);
  kan_gemm<<<512, 256, 0, stream>>>(x, Bt, bkn, C0, bscv, bshv, sscv, sshv, out);
}

// Round 4
// 151.166 us; speedup vs baseline: 1.2156x; 1.0257x over previous
//
#include <hip/hip_runtime.h>
#include <stdint.h>
#include <stddef.h>

typedef _Float16 h2 __attribute__((ext_vector_type(2)));
typedef _Float16 h8 __attribute__((ext_vector_type(8)));
typedef float f4 __attribute__((ext_vector_type(4)));

union Hfrag { h2 p[4]; h8 v; };

// ---------------- workspace layout (bytes) ----------------
// pmin/pmax (K1 partials) are dead after K2; Bt (built in K3) overlays pmin.
#define WS_PMIN   0               // f32 [512][256] = 512 KB
#define WS_PMAX   524288          // f32 [512][256] = 512 KB
#define WS_BT     0               // f16 [40 ks][2 half][128 o][32 kk] = 655,360 B
#define WS_SMALL  1048576
#define WS_SCALEV (WS_SMALL + 0)      // f32 [256]
#define WS_BKN    (WS_SMALL + 1024)   // f16 [4][256] knot offsets b_j
#define WS_C0     (WS_SMALL + 3072)   // f32 [256] folded constant column
#define WS_BSC    (WS_SMALL + 4096)
#define WS_BSH    (WS_SMALL + 5120)
#define WS_SSC    (WS_SMALL + 6144)
#define WS_SSH    (WS_SMALL + 7168)

// ---------------- K1: per-feature min/max partials ----------------
__global__ __launch_bounds__(256) void kan_minmax(const float* __restrict__ x,
                                                  float* __restrict__ pmin,
                                                  float* __restrict__ pmax) {
  __shared__ f4 smn[4][64], smx[4][64];
  const int b = blockIdx.x, t = threadIdx.x;
  const int fq = t & 63, rg = t >> 6;
  const float* p = x + (size_t)b * 64 * 256 + (size_t)rg * 16 * 256 + fq * 4;
  f4 mn = (f4)(3.402823466e38f), mx = (f4)(-3.402823466e38f);
#pragma unroll
  for (int j = 0; j < 16; ++j) {
    f4 v = *(const f4*)(p + (size_t)j * 256);
    mn = __builtin_elementwise_min(mn, v);
    mx = __builtin_elementwise_max(mx, v);
  }
  smn[rg][fq] = mn; smx[rg][fq] = mx;
  __syncthreads();
  if (rg == 0) {
#pragma unroll
    for (int g = 1; g < 4; ++g) {
      mn = __builtin_elementwise_min(mn, smn[g][fq]);
      mx = __builtin_elementwise_max(mx, smx[g][fq]);
    }
    *(f4*)(pmin + (size_t)b * 256 + fq * 4) = mn;
    *(f4*)(pmax + (size_t)b * 256 + fq * 4) = mx;
  }
}

// ---------------- K2: finalize minmax -> scalev, knot offsets, BN consts ----
// 64 blocks x 256 threads; block q covers features 4q..4q+3 (f4 columns).
// Thread t reduces partial rows t and t+256; LDS f4 tree to one f4.
// b_j = mn + j*0.25*(mx-mn+eps): relu(xn - j/4) == scalev * relu(x - b_j).
__global__ __launch_bounds__(256) void kan_finalize(
    const float* __restrict__ pmin, const float* __restrict__ pmax,
    const float* __restrict__ g1, const float* __restrict__ b1,
    const float* __restrict__ m1, const float* __restrict__ v1,
    const float* __restrict__ g2, const float* __restrict__ b2,
    const float* __restrict__ m2, const float* __restrict__ v2,
    float* __restrict__ scalev, _Float16* __restrict__ bkn,
    float* __restrict__ bscv, float* __restrict__ bshv,
    float* __restrict__ sscv, float* __restrict__ sshv) {
  __shared__ f4 smn[256], smx[256];
  const int t = threadIdx.x, q = blockIdx.x;
  const float* pm = pmin + (size_t)t * 256 + q * 4;
  const float* px = pmax + (size_t)t * 256 + q * 4;
  f4 mn = __builtin_elementwise_min(*(const f4*)pm, *(const f4*)(pm + 256 * 256));
  f4 mx = __builtin_elementwise_max(*(const f4*)px, *(const f4*)(px + 256 * 256));
  smn[t] = mn; smx[t] = mx;
  __syncthreads();
  for (int st = 128; st > 0; st >>= 1) {
    if (t < st) {
      smn[t] = __builtin_elementwise_min(smn[t], smn[t + st]);
      smx[t] = __builtin_elementwise_max(smx[t], smx[t + st]);
    }
    __syncthreads();
  }
  if (t == 0) {
    const f4 fmn = smn[0], fmx = smx[0];
#pragma unroll
    for (int j = 0; j < 4; ++j) {
      const int o = q * 4 + j;
      const float mnS = fmn[j], mxS = fmx[j];
      const float rng = mxS - mnS + 1e-7f;
      scalev[o] = 1.0f / rng;
      const float step = 0.25f * rng;
#pragma unroll
      for (int jj = 0; jj < 4; ++jj)
        bkn[jj * 256 + o] = (_Float16)(mnS + step * (float)jj);
      const float bs = g1[o] / sqrtf(v1[o] + 1e-3f);
      bscv[o] = bs;
      bshv[o] = b1[o] - m1[o] * bs;
      const float ss = g2[o] / sqrtf(v2[o] + 1e-3f);
      sscv[o] = ss;
      sshv[o] = b2[o] - m2[o] * ss;
    }
  }
}

// ---------------- K3: build reduced f16 weight matrix Bt + C0 ----------------
// 8 triangle bases on xn in [0,1) span {1, xn, relu(xn-1/4), relu(xn-1/2),
// relu(xn-3/4)}.  Const column -> C0 (folded into spline-BN shift); scale sc
// folds into Bt so GEMM A-columns are relu(x - b_j) on raw x (f16).
// Bt flat: [(ks*2 + half)*128 + o]*32 + kk ; ks = j*8+ic (spline j=0..3),
// ks = 32+ic (base, value = base_w[i, o]).  i = ic*32+kk.
__global__ __launch_bounds__(256) void kan_buildw(
    const float* __restrict__ spline_w, const float* __restrict__ spline_s,
    const float* __restrict__ base_w, const float* __restrict__ scalev,
    _Float16* __restrict__ Bt, float* __restrict__ C0) {
  const int og = blockIdx.x;   // 256 blocks: one output feature each
  const int i  = threadIdx.x;  // input feature
  const float* wp = spline_w + (size_t)(og * 256 + i) * 9;
  const float w1 = wp[1], w2 = wp[2], w3 = wp[3], w4 = wp[4];
  const float w5 = wp[5], w6 = wp[6], w7 = wp[7], w8 = wp[8];
  const float s  = spline_s[og * 256 + i];
  const float sc = scalev[i];
  const float wp0 = 0.25f*w1 + 0.5f*w2 + 0.75f*w3 + w4 + 0.75f*w5 + 0.5f*w6 + 0.25f*w7;
  float wj[4];
  wj[0] = (w5 + w6 + w7 + w8) - (w1 + w2 + w3 + w4);  // xn column
  wj[1] = w1 - 2.0f * w5;                             // relu(xn-1/4)
  wj[2] = w2 - 2.0f * w6;                             // relu(xn-1/2)
  wj[3] = w3 - 2.0f * w7;                             // relu(xn-3/4)
  const float ssc = s * sc;
  const int half = og >> 7, o = og & 127, ic = i >> 5, kk = i & 31;
#pragma unroll
  for (int j = 0; j < 4; ++j) {
    const int ks = j * 8 + ic;
    Bt[((size_t)(ks * 2 + half) * 128 + o) * 32 + kk] = (_Float16)(wj[j] * ssc);
  }
  Bt[((size_t)((32 + ic) * 2 + half) * 128 + o) * 32 + kk] =
      (_Float16)base_w[(size_t)i * 256 + og];
  __shared__ float red[256];
  red[i] = wp0 * s;
  __syncthreads();
  for (int st = 128; st > 0; st >>= 1) {
    if (i < st) red[i] += red[i + st];
    __syncthreads();
  }
  if (i == 0) C0[og] = red[0];
}

// ---------------- K4: fused dual GEMM + BN + SiLU ----------------
// 128x128 tile, 4 waves (2x2), 16x16x32 f16 MFMA.  5 MFMA sub-steps per
// K-chunk (4 spline cols + base).  FIFO-clean software pipeline:
//  - B frags for sub-step k+1 issued into the OTHER named ping-pong set
//    (bfA/bfB, constant-indexed only -> registers) before sub-step k's MFMAs,
//    so each MFMA's vmcnt wait drains only L2-fast loads one step old;
//  - x prefetch (HBM ~900cy) is issued DEAD LAST, pinned by sched_barrier(0):
//    vmcnt is FIFO, so any older HBM load would stall every B-frag wait.
__global__ __launch_bounds__(256, 2) void kan_gemm(
    const float* __restrict__ x, const _Float16* __restrict__ Bt,
    const _Float16* __restrict__ bkn, const float* __restrict__ C0,
    const float* __restrict__ bscv, const float* __restrict__ bshv,
    const float* __restrict__ sscv, const float* __restrict__ sshv,
    float* __restrict__ out) {
  const int tid = threadIdx.x;
  const int lane = tid & 63;
  const int wv = tid >> 6;
  const int wm = wv >> 1, wn = wv & 1;
  const int lr = lane & 15, lg = lane >> 4;
  const int mt = blockIdx.x & 255, nt = blockIdx.x >> 8;

  const int rowA = mt * 128 + wm * 64 + lr;
  const int colB = wn * 64 + lr;

  f4 accS[4][4], accB[4][4];
#pragma unroll
  for (int m = 0; m < 4; ++m)
#pragma unroll
    for (int n = 0; n < 4; ++n) { accS[m][n] = (f4)0.0f; accB[m][n] = (f4)0.0f; }

  const char* btbase = (const char*)Bt + (size_t)nt * 8192 + (size_t)colB * 64 + (size_t)lg * 16;

  h2 hz; hz[0] = (_Float16)0.0f; hz[1] = (_Float16)0.0f;

  f4 xa[4], xb[4];
  { // prologue: x fragment for ic=0
    const int ib = lg * 8;
#pragma unroll
    for (int m = 0; m < 4; ++m) {
      const float* px = x + (size_t)(rowA + m * 16) * 256 + ib;
      xa[m] = *(const f4*)px; xb[m] = *(const f4*)(px + 4);
    }
  }

// spline sub-step J: bbj load (L2-hot; waits drain only same-age B loads),
// per-m A-frag gen fused with its 4 MFMAs (keeps live regs small).
#define SPLINE_STEP(J, BF)                                                   \
  {                                                                          \
    Hfrag bbj;                                                               \
    bbj.v = *(const h8*)(bkn + (J) * 256 + ic * 32 + lg * 8);                \
    _Pragma("unroll")                                                        \
    for (int m = 0; m < 4; ++m) {                                            \
      Hfrag afm;                                                             \
      _Pragma("unroll")                                                      \
      for (int qq = 0; qq < 4; ++qq) {                                       \
        h2 d = xh[m].p[qq] - bbj.p[qq];                                      \
        afm.p[qq] = __builtin_elementwise_max(d, hz);                        \
      }                                                                      \
      _Pragma("unroll")                                                      \
      for (int n = 0; n < 4; ++n)                                            \
        accS[m][n] = __builtin_amdgcn_mfma_f32_16x16x32_f16(afm.v, BF[n].v,  \
                                                            accS[m][n], 0, 0, 0); \
    }                                                                        \
  }

#define LOADB(BF, BYTEOFF)                                                   \
  _Pragma("unroll")                                                          \
  for (int n = 0; n < 4; ++n)                                                \
    BF[n].v = *(const h8*)(bpic + (BYTEOFF) + n * 1024);

#pragma unroll 1
  for (int ic = 0; ic < 8; ++ic) {
    const char* bpic = btbase + (size_t)ic * 16384;

    Hfrag bfA[4], bfB[4];
    LOADB(bfA, 0)                      // ks = ic       (sub-step 0)

    // x -> f16 (RTE), A-fragment layout (VALU overlaps the loads above)
    Hfrag xh[4];
#pragma unroll
    for (int m = 0; m < 4; ++m) {
      xh[m].p[0][0] = (_Float16)xa[m].x; xh[m].p[0][1] = (_Float16)xa[m].y;
      xh[m].p[1][0] = (_Float16)xa[m].z; xh[m].p[1][1] = (_Float16)xa[m].w;
      xh[m].p[2][0] = (_Float16)xb[m].x; xh[m].p[2][1] = (_Float16)xb[m].y;
      xh[m].p[3][0] = (_Float16)xb[m].z; xh[m].p[3][1] = (_Float16)xb[m].w;
    }

    LOADB(bfB, 131072)                 // ks = 8+ic     (sub-step 1, 1 ahead)
    SPLINE_STEP(0, bfA)
    LOADB(bfA, 262144)                 // ks = 16+ic    (sub-step 2)
    SPLINE_STEP(1, bfB)
    LOADB(bfB, 393216)                 // ks = 24+ic    (sub-step 3)
    SPLINE_STEP(2, bfA)
    LOADB(bfA, 524288)                 // ks = 32+ic    (base weights)
    SPLINE_STEP(3, bfB)

    // base sub-step: A = f16(x) verbatim
#pragma unroll
    for (int m = 0; m < 4; ++m)
#pragma unroll
      for (int n = 0; n < 4; ++n)
        accB[m][n] = __builtin_amdgcn_mfma_f32_16x16x32_f16(xh[m].v, bfA[n].v, accB[m][n], 0, 0, 0);

    // x prefetch LAST (FIFO: must be newer than every B load of this chunk)
    __builtin_amdgcn_sched_barrier(0);
    if (ic < 7) {
      const int ib = (ic + 1) * 32 + lg * 8;
#pragma unroll
      for (int m = 0; m < 4; ++m) {
        const float* px = x + (size_t)(rowA + m * 16) * 256 + ib;
        xa[m] = *(const f4*)px; xb[m] = *(const f4*)(px + 4);
      }
    }
  }
#undef SPLINE_STEP
#undef LOADB

  // epilogue: out = silu(accB*bs + bsh) + accS*ss + (ssh + ss*C0)
#pragma unroll
  for (int n = 0; n < 4; ++n) {
    const int col = nt * 128 + colB + n * 16;
    const float vbs = bscv[col], vbh = bshv[col];
    const float vss = sscv[col];
    const float vsh = sshv[col] + vss * C0[col];
#pragma unroll
    for (int m = 0; m < 4; ++m) {
      const int row0 = mt * 128 + wm * 64 + m * 16 + lg * 4;
#pragma unroll
      for (int r = 0; r < 4; ++r) {
        const float zb = accB[m][n][r] * vbs + vbh;
        const float si = zb / (1.0f + __expf(-zb));
        const float val = si + accS[m][n][r] * vss + vsh;
        out[(size_t)(row0 + r) * 256 + col] = val;
      }
    }
  }
}

extern "C" void kernel_launch(void* const* d_in, const int* in_sizes, int n_in,
                              void* d_out, int out_size, void* d_ws, size_t ws_size,
                              hipStream_t stream) {
  const float* x        = (const float*)d_in[0];
  const float* base_w   = (const float*)d_in[1];
  const float* spline_w = (const float*)d_in[2];
  const float* spline_s = (const float*)d_in[3];
  const float* g1 = (const float*)d_in[4];
  const float* b1 = (const float*)d_in[5];
  const float* m1 = (const float*)d_in[6];
  const float* v1 = (const float*)d_in[7];
  const float* g2 = (const float*)d_in[8];
  const float* b2 = (const float*)d_in[9];
  const float* m2 = (const float*)d_in[10];
  const float* v2 = (const float*)d_in[11];
  float* out = (float*)d_out;
  char* ws = (char*)d_ws;

  float* pmin     = (float*)(ws + WS_PMIN);
  float* pmax     = (float*)(ws + WS_PMAX);
  _Float16* Bt    = (_Float16*)(ws + WS_BT);
  float* scalev   = (float*)(ws + WS_SCALEV);
  _Float16* bkn   = (_Float16*)(ws + WS_BKN);
  float* C0       = (float*)(ws + WS_C0);
  float* bscv     = (float*)(ws + WS_BSC);
  float* bshv     = (float*)(ws + WS_BSH);
  float* sscv     = (float*)(ws + WS_SSC);
  float* sshv     = (float*)(ws + WS_SSH);

  kan_minmax<<<512, 256, 0, stream>>>(x, pmin, pmax);
  kan_finalize<<<64, 256, 0, stream>>>(pmin, pmax, g1, b1, m1, v1, g2, b2, m2, v2,
                                       scalev, bkn, bscv, bshv, sscv, sshv);
  kan_buildw<<<256, 256, 0, stream>>>(spline_w, spline_s, base_w, scalev, Bt, C0);
  kan_gemm<<<512, 256, 0, stream>>>(x, Bt, bkn, C0, bscv, bshv, sscv, sshv, out);
}